// Round 2
// 298.339 us; speedup vs baseline: 1.0414x; 1.0414x over previous
//
#include <hip/hip_runtime.h>

// PLoss fused kernel, round 4 (= round-3 structure + workspace-size guard).
// Round-3 bench died with a container-level failure (no counters). Audit found
// one plausible crash vector: round 3 wrote grid(=1536) floats of per-block
// partials into d_ws without checking ws_size (round 2 only ever used 4 B).
// If ws_size < 6 KB those stores are OOB device writes -> container death.
// This round clamps grid to ws_size/4. Everything else unchanged:
//  - Wave-private 64-row tiles (wave w owns rows w*16..w*16+15, all 128 proto
//    cols) -> ZERO per-tile __syncthreads, no cross-wave argmin combine.
//  - Protos staged once per block as frag-linear bf16 MFMA-B fragments (32 KB
//    LDS); 32 conflict-free ds_read_b128/wave/tile.
//  - Register double-buffer prefetch of next tile's x + labels.
//  - Softmax reduce depth 2; packed argmin: 8 in-register candidates + 4
//    shuffles per output row.
//  - partial[blockIdx] overwrite (no atomics, no memset dispatch); finalize
//    sums in double.

#define C_DIM 128
#define TILE_ROWS 64
#define NTHREADS 256
#define XSTRIDE 136           // ushorts per x row: 128 + 8 pad
#define GRID_MAX 1536
#define NFRAG 32              // 8 n-tiles * 4 k-tiles

typedef __bf16 bf16x8 __attribute__((ext_vector_type(8)));
typedef unsigned short ushort8 __attribute__((ext_vector_type(8)));
typedef float f32x4 __attribute__((ext_vector_type(4)));

union FragU { ushort8 u; bf16x8 b; };

__device__ __forceinline__ unsigned short f2bf(float f) {
    unsigned int u = __float_as_uint(f);
    u += 0x7fffu + ((u >> 16) & 1u);   // round-to-nearest-even
    return (unsigned short)(u >> 16);
}
__device__ __forceinline__ float bf2f(unsigned short h) {
    return __uint_as_float(((unsigned int)h) << 16);
}
// order-preserving float->uint (min-compatible)
__device__ __forceinline__ unsigned f2ord(float s) {
    unsigned u = __float_as_uint(s);
    return (u & 0x80000000u) ? ~u : (u | 0x80000000u);
}
__device__ __forceinline__ float fmax4(float4 v) {
    return fmaxf(fmaxf(v.x, v.y), fmaxf(v.z, v.w));
}
__device__ __forceinline__ float esum4(float4 v, float m) {
    return __expf(v.x - m) + __expf(v.y - m) + __expf(v.z - m) + __expf(v.w - m);
}

extern "C" __global__ void __launch_bounds__(NTHREADS, 3)
ploss_main(const float* __restrict__ x, const int* __restrict__ labels,
           const float* __restrict__ protos, const int* __restrict__ kptr,
           float* __restrict__ partial, int n_tiles, int n_rows)
{
    // 32768 + 17408 + 256 + 512 + 16 = 50.9 KB -> 3 blocks/CU
    __shared__ __attribute__((aligned(16))) unsigned short blds[NFRAG * 64 * 8];
    __shared__ __attribute__((aligned(16))) unsigned short x_lds[TILE_ROWS * XSTRIDE];
    __shared__ float lse_lds[TILE_ROWS];
    __shared__ float norm_lds[C_DIM];
    __shared__ float wsum[4];

    const int tid  = threadIdx.x;
    const int lane = tid & 63;
    const int wave = tid >> 6;
    const int l15  = lane & 15;
    const int quad = lane >> 4;
    const int r_l  = lane >> 2;         // row 0..15 within wave's 16 (load/softmax)
    const int c_l  = (lane & 3) * 32;   // 32-col chunk within row
    const int wrow = wave * 16;
    const bool epi = (l15 == 0);
    const int kk = kptr[0];

    // ---- prologue: proto squared norms (2 threads per proto) ----
    {
        const int j = tid >> 1;
        const float* pr = protos + j * C_DIM + (tid & 1) * 64;
        float s = 0.f;
#pragma unroll
        for (int c = 0; c < 64; c += 4) {
            float4 v = *(const float4*)(pr + c);
            s += v.x*v.x + v.y*v.y + v.z*v.z + v.w*v.w;
        }
        s += __shfl_xor(s, 1);
        if ((tid & 1) == 0) norm_lds[j] = s;
    }
    // ---- prologue: protos -> frag-linear bf16 MFMA-B fragments in LDS ----
    // frag id = nt*4+kt; lane l holds col nt*16+(l&15), k = kt*32+(l>>4)*8..+8
#pragma unroll
    for (int f = 0; f < 8; ++f) {
        const int g = f * NTHREADS + tid;       // 0..2047 = frag*64 + lane
        const int l = g & 63;
        const int frag = g >> 6;
        const int nt = frag >> 2, kt = frag & 3;
        const float* pp = protos + (nt * 16 + (l & 15)) * C_DIM + kt * 32 + (l >> 4) * 8;
        float4 v0 = *(const float4*)(pp);
        float4 v1 = *(const float4*)(pp + 4);
        FragU fr;
        fr.u[0]=f2bf(v0.x); fr.u[1]=f2bf(v0.y); fr.u[2]=f2bf(v0.z); fr.u[3]=f2bf(v0.w);
        fr.u[4]=f2bf(v1.x); fr.u[5]=f2bf(v1.y); fr.u[6]=f2bf(v1.z); fr.u[7]=f2bf(v1.w);
        *(ushort8*)&blds[g * 8] = fr.u;
    }
    __syncthreads();   // blds + norm_lds ready; last workgroup barrier until reduce

    float p2h[8];
#pragma unroll
    for (int nt = 0; nt < 8; ++nt) p2h[nt] = 0.5f * norm_lds[nt * 16 + l15];

    float nll_acc = 0.f;

    // ---- prologue: load first tile into registers ----
    int t = blockIdx.x;
    float4 a[8];
    int4 lab4 = {0, 0, 0, 0};
    {
        long long rb = (long long)t * TILE_ROWS + wrow + r_l;
        if (rb >= n_rows) rb = n_rows - 1;
        const float* xr = x + rb * C_DIM + c_l;
#pragma unroll
        for (int i = 0; i < 8; ++i) a[i] = *(const float4*)(xr + i * 4);
        if (epi) {
            long long lb = (long long)t * TILE_ROWS + wrow + quad * 4;
            if (lb > (long long)n_rows - 4) lb = n_rows - 4;
            lab4 = *(const int4*)(labels + lb);
        }
    }

    for (; t < n_tiles; t += gridDim.x) {
        // ---- prefetch next tile (x + labels) into shadow registers ----
        const int tn = t + gridDim.x;
        const int tl = (tn < n_tiles) ? tn : t;    // clamp: tail load discarded
        float4 b[8];
        int4 labn4 = lab4;
        {
            long long rb = (long long)tl * TILE_ROWS + wrow + r_l;
            if (rb >= n_rows) rb = n_rows - 1;
            const float* xr = x + rb * C_DIM + c_l;
#pragma unroll
            for (int i = 0; i < 8; ++i) b[i] = *(const float4*)(xr + i * 4);
            if (epi) {
                long long lb = (long long)tl * TILE_ROWS + wrow + quad * 4;
                if (lb > (long long)n_rows - 4) lb = n_rows - 4;
                labn4 = *(const int4*)(labels + lb);
            }
        }

        // ---- softmax stats (4 lanes per row, depth-2 reduce) ----
        float m = fmax4(a[0]);
#pragma unroll
        for (int i = 1; i < 8; ++i) m = fmaxf(m, fmax4(a[i]));
        float s = 0.f;
#pragma unroll
        for (int i = 0; i < 8; ++i) s += esum4(a[i], m);
#pragma unroll
        for (int mask = 1; mask <= 2; mask <<= 1) {
            float mo = __shfl_xor(m, mask);
            float so = __shfl_xor(s, mask);
            float nm = fmaxf(m, mo);
            s = s * __expf(m - nm) + so * __expf(mo - nm);
            m = nm;
        }
        if ((lane & 3) == 0) lse_lds[wrow + r_l] = m + __logf(s);

        // ---- bf16 convert -> wave-private LDS rows ----
        ushort8* dst = (ushort8*)&x_lds[(wrow + r_l) * XSTRIDE + c_l];
#pragma unroll
        for (int i = 0; i < 4; ++i) {
            float4 v0 = a[2 * i], v1 = a[2 * i + 1];
            FragU wv;
            wv.u[0]=f2bf(v0.x); wv.u[1]=f2bf(v0.y); wv.u[2]=f2bf(v0.z); wv.u[3]=f2bf(v0.w);
            wv.u[4]=f2bf(v1.x); wv.u[5]=f2bf(v1.y); wv.u[6]=f2bf(v1.z); wv.u[7]=f2bf(v1.w);
            dst[i] = wv.u;
        }
        // same-wave DS ordering: drain writes before fragment reads (no barrier)
        asm volatile("s_waitcnt lgkmcnt(0)" ::: "memory");
        __builtin_amdgcn_sched_barrier(0);

        // ---- MFMA: this wave's 16 rows x all 128 protos ----
        FragU A[4];
#pragma unroll
        for (int kt = 0; kt < 4; ++kt)
            A[kt].u = *(const ushort8*)&x_lds[(wrow + l15) * XSTRIDE + kt * 32 + quad * 8];
        f32x4 acc[8];
        f32x4 zero = {0.f, 0.f, 0.f, 0.f};
#pragma unroll
        for (int nt = 0; nt < 8; ++nt) acc[nt] = zero;
#pragma unroll
        for (int kt = 0; kt < 4; ++kt) {
#pragma unroll
            for (int nt = 0; nt < 8; ++nt) {
                FragU B;
                B.u = *(const ushort8*)&blds[((nt * 4 + kt) * 64 + lane) * 8];
                acc[nt] = __builtin_amdgcn_mfma_f32_16x16x32_bf16(A[kt].b, B.b, acc[nt], 0, 0, 0);
            }
        }

        // ---- in-wave packed argmin over all 128 cols ----
        // C layout: col = nt*16 + l15, row = quad*4 + reg
        unsigned res[4];
#pragma unroll
        for (int rg = 0; rg < 4; ++rg) {
            unsigned u = 0xFFFFFFFFu;
#pragma unroll
            for (int nt = 0; nt < 8; ++nt) {
                unsigned c = (f2ord(p2h[nt] - acc[nt][rg]) & 0xFFFFFF80u)
                           | (unsigned)(nt * 16 + l15);
                u = (c < u) ? c : u;
            }
#pragma unroll
            for (int mask = 1; mask <= 8; mask <<= 1) {
                unsigned uo = __shfl_xor(u, mask);
                u = (uo < u) ? uo : u;
            }
            res[rg] = u;
        }

        // ---- per-wave epilogue (4 lanes, rows quad*4..quad*4+3) ----
        if (epi) {
#pragma unroll
            for (int rg = 0; rg < 4; ++rg) {
                const int row16 = quad * 4 + rg;
                const long long grow = (long long)t * TILE_ROWS + wrow + row16;
                if (grow < n_rows) {
                    int lab;
                    if      (rg == 0) lab = lab4.x;
                    else if (rg == 1) lab = lab4.y;
                    else if (rg == 2) lab = lab4.z;
                    else              lab = lab4.w;
                    const int bj  = (int)(res[rg] & 127u);
                    const int eff = (lab <= kk - 1) ? lab : bj;
                    const float xv = bf2f(x_lds[(wrow + row16) * XSTRIDE + eff]);
                    nll_acc += lse_lds[wrow + row16] - xv;
                }
            }
        }

        // rotate prefetch buffers
#pragma unroll
        for (int i = 0; i < 8; ++i) a[i] = b[i];
        lab4 = labn4;
    }

    // ---- block reduce -> per-block partial (no atomics, no memset needed) ----
    float v = nll_acc;
#pragma unroll
    for (int mask = 1; mask <= 32; mask <<= 1) v += __shfl_xor(v, mask);
    if (lane == 0) wsum[wave] = v;
    __syncthreads();
    if (tid == 0) partial[blockIdx.x] = wsum[0] + wsum[1] + wsum[2] + wsum[3];
}

extern "C" __global__ void __launch_bounds__(256)
ploss_finalize(const float* __restrict__ partial, float* __restrict__ out,
               float inv_n, int nparts)
{
    __shared__ double sm[4];
    const int tid = threadIdx.x, lane = tid & 63, wave = tid >> 6;
    double v = 0.0;
    for (int i = tid; i < nparts; i += 256) v += (double)partial[i];
#pragma unroll
    for (int mask = 1; mask <= 32; mask <<= 1) v += __shfl_xor(v, mask);
    if (lane == 0) sm[wave] = v;
    __syncthreads();
    if (tid == 0) out[0] = (float)((sm[0] + sm[1] + sm[2] + sm[3]) * (double)inv_n);
}

extern "C" void kernel_launch(void* const* d_in, const int* in_sizes, int n_in,
                              void* d_out, int out_size, void* d_ws, size_t ws_size,
                              hipStream_t stream)
{
    const float* x      = (const float*)d_in[0];
    const int*   labels = (const int*)d_in[1];
    const float* protos = (const float*)d_in[2];
    const int*   kptr   = (const int*)d_in[3];
    const int n_rows  = in_sizes[0] / C_DIM;                 // element counts
    const int n_tiles = (n_rows + TILE_ROWS - 1) / TILE_ROWS; // 400000/64 = 6250

    float* partial = (float*)d_ws;   // overwritten every call; poison-safe

    int grid = GRID_MAX;
    if (grid > n_tiles) grid = n_tiles;
    // Workspace guard: never write more partials than d_ws can hold.
    // (Suspected round-3 container crash: grid*4 B > ws_size -> OOB stores.)
    const int max_parts = (int)(ws_size / sizeof(float));
    if (grid > max_parts) grid = max_parts;
    if (grid < 1) grid = 1;          // degenerate-ws fallback: single block

    ploss_main<<<grid, NTHREADS, 0, stream>>>(x, labels, protos, kptr, partial,
                                              n_tiles, n_rows);
    ploss_finalize<<<1, 256, 0, stream>>>(partial, (float*)d_out,
                                          1.0f / (float)n_rows, grid);
}